// Round 6
// baseline (123.347 us; speedup 1.0000x reference)
//
#include <hip/hip_runtime.h>
#include <hip/hip_bf16.h>

// feature [B=128, E=64, D=128] fp32 -> N = 8192 rows of dim 128.
// loss = mean_r( log(den_r) - log(pos_r) ),
//   den_r = sum_c exp(10*<f_r,f_c>), pos_r = sum over c in r's 64-row block.
// Symmetric formulation: gram is symmetric and MFMA dots are bitwise
// commutative, so compute only unordered 64-row-strip pairs {I,J} (8256 of
// 16384 supertiles); each off-diag supertile's exp values feed den twice
// (row-sums -> strip I, col-sums -> strip J). 64-strips == E-blocks, so
// pos = row-sums of diagonal supertiles.
#define N_ROWS 8192
#define DIM    128
#define EXPTEN 22026.465794806718f  // exp(10.0)
// Xb = normalize(f) * SCALE, SCALE^2 = 10*log2(e); then exp2(dot) = exp(10*<f,f>)
#define SCALE  3.7982826f

typedef __attribute__((ext_vector_type(8))) short short8;   // 8 bf16 = 4 VGPRs
typedef __attribute__((ext_vector_type(4))) float floatx4;  // MFMA C/D

#define EXP2F(x) __builtin_amdgcn_exp2f(x)

// ---- Kernel 1: L2-normalize rows, scale, cast to bf16; zero pos/den ----
__global__ void norm_kernel(const float* __restrict__ F, __hip_bfloat16* __restrict__ Xb,
                            float* __restrict__ pos, float* __restrict__ den) {
    int lane = threadIdx.x & 63;
    int wave = threadIdx.x >> 6;
    int row  = blockIdx.x * 4 + wave;           // 2048 blocks x 4 waves = 8192 rows
    const float2 v = *(const float2*)(F + (size_t)row * DIM + lane * 2);
    float ss = v.x * v.x + v.y * v.y;
    #pragma unroll
    for (int m = 1; m < 64; m <<= 1) ss += __shfl_xor(ss, m);
    float inv = rsqrtf(ss) * SCALE;
    __hip_bfloat162 o;
    o.x = __float2bfloat16(v.x * inv);
    o.y = __float2bfloat16(v.y * inv);
    *((__hip_bfloat162*)(Xb + (size_t)row * DIM) + lane) = o;
    if (lane == 0) { pos[row] = 0.f; den[row] = 0.f; }
}

// ---- Kernel 2: symmetric fused gram + exp + row/col sums ----
// Block (i, d): strip pair I=i, J=(i+d)&127 (64-row strips). d=0 diagonal;
// d=64 deduplicated (i<64 only). 4 waves in 2x2: wave-tile 32x32 via 2x2
// MFMA 16x16x32 bf16. A and B fragments loaded DIRECTLY from global
// (16 x b128 per wave, one waitcnt) -- no LDS, no __syncthreads: the
// barrier-drain stall class (r3/r5 plateau) is structurally removed.
// Wave-duplicate loads hit per-CU L1 (each strip is 16 KB). 8256 blocks
// ~= 32/CU stream; launch_bounds(256,4) -> 16 waves/CU, ~100 VGPR (no spill;
// r4 showed spill = 2x catastrophe, so acc/partials kept minimal).
__global__ __launch_bounds__(256, 4) void gram_kernel(
        const __hip_bfloat16* __restrict__ Xb,
        float* __restrict__ pos, float* __restrict__ den) {
    const int i = blockIdx.x;         // 0..127 row strip
    const int d = blockIdx.y;         // 0..64 circular distance
    if (d == 64 && i >= 64) return;   // dedup distance-64 pairs
    const int J = (i + d) & 127;

    const int tid  = threadIdx.x;
    const int lane = tid & 63;
    const int wave = tid >> 6;
    const int wm   = wave >> 1, wn = wave & 1;
    const int quad = lane >> 4;       // 0..3
    const int l15  = lane & 15;       // 0..15

    const int R0 = i * 64;            // global row base
    const int C0 = J * 64;            // global col base

    // A fragments: rows R0+wm*32+mi*16+l15, elems ko*32+quad*8.
    // B fragments: rows C0+wn*32+nl*16+l15 (gram B-operand = X row, same layout).
    short8 af[2][4], bf[2][4];
    {
        const __hip_bfloat16* Ab = Xb + ((size_t)(R0 + wm * 32 + l15)) * DIM + quad * 8;
        const __hip_bfloat16* Bb = Xb + ((size_t)(C0 + wn * 32 + l15)) * DIM + quad * 8;
        #pragma unroll
        for (int mi = 0; mi < 2; ++mi)
            #pragma unroll
            for (int ko = 0; ko < 4; ++ko) {
                af[mi][ko] = *(const short8*)(Ab + mi * 16 * DIM + ko * 32);
                bf[mi][ko] = *(const short8*)(Bb + mi * 16 * DIM + ko * 32);
            }
    }

    floatx4 acc[2][2];
    #pragma unroll
    for (int mi = 0; mi < 2; ++mi)
        #pragma unroll
        for (int nl = 0; nl < 2; ++nl) acc[mi][nl] = (floatx4)0.0f;

    #pragma unroll
    for (int ko = 0; ko < 4; ++ko)
        #pragma unroll
        for (int mi = 0; mi < 2; ++mi)
            #pragma unroll
            for (int nl = 0; nl < 2; ++nl)
                acc[mi][nl] = __builtin_amdgcn_mfma_f32_16x16x32_bf16(
                    af[mi][ko], bf[nl][ko], acc[mi][nl], 0, 0, 0);

    // Epilogue: exp2 each element once; accumulate row partials (32 cols of
    // this wave) and col partials (32 rows of this wave).
    const bool d0 = (d == 0);
    float rs[2][4];                    // [mi][rg] row partials
    float cs[2] = {0.f, 0.f};          // [nl]     col partials
    #pragma unroll
    for (int mi = 0; mi < 2; ++mi)
        #pragma unroll
        for (int rg = 0; rg < 4; ++rg) rs[mi][rg] = 0.f;

    #pragma unroll
    for (int mi = 0; mi < 2; ++mi)
        #pragma unroll
        for (int nl = 0; nl < 2; ++nl)
            #pragma unroll
            for (int rg = 0; rg < 4; ++rg) {
                float ev = EXP2F(acc[mi][nl][rg]);
                // exact diagonal: row==col -> exp(10*||x||^2) == exp(10)
                if (d0 && wm == wn && mi == nl && l15 == quad * 4 + rg)
                    ev = EXPTEN;
                rs[mi][rg] += ev;
                cs[nl] += ev;
            }

    // Row sums: reduce over the 16 l15 lanes (cols within quad), one atomic
    // per row per wave. Diagonal supertile row-sums are also the pos sums.
    #pragma unroll
    for (int mi = 0; mi < 2; ++mi)
        #pragma unroll
        for (int rg = 0; rg < 4; ++rg) {
            float v = rs[mi][rg];
            #pragma unroll
            for (int m = 1; m < 16; m <<= 1) v += __shfl_xor(v, m);
            if (l15 == 0) {
                int r = R0 + wm * 32 + mi * 16 + quad * 4 + rg;
                atomicAdd(&den[r], v);
                if (d0) atomicAdd(&pos[r], v);
            }
        }

    // Col sums (off-diagonal only: the transpose block's row contribution).
    if (!d0) {
        #pragma unroll
        for (int nl = 0; nl < 2; ++nl) {
            float v = cs[nl];
            v += __shfl_xor(v, 16);
            v += __shfl_xor(v, 32);    // now summed over all 4 quads (32 rows)
            if (quad == 0)
                atomicAdd(&den[C0 + wn * 32 + nl * 16 + l15], v);
        }
    }
}

// ---- Kernel 3: loss = mean(log(den/pos)) ----
__global__ void loss_kernel(const float* __restrict__ pos, const float* __restrict__ den,
                            float* __restrict__ out) {
    __shared__ float red[4];
    float acc = 0.f;
    for (int ii = threadIdx.x; ii < N_ROWS / 4; ii += 256) {
        float4 dv = ((const float4*)den)[ii];
        float4 pv = ((const float4*)pos)[ii];
        acc += __logf(dv.x / pv.x) + __logf(dv.y / pv.y) +
               __logf(dv.z / pv.z) + __logf(dv.w / pv.w);
    }
    #pragma unroll
    for (int m = 1; m < 64; m <<= 1) acc += __shfl_xor(acc, m);
    int lane = threadIdx.x & 63, w = threadIdx.x >> 6;
    if (lane == 0) red[w] = acc;
    __syncthreads();
    if (threadIdx.x == 0)
        out[0] = (red[0] + red[1] + red[2] + red[3]) * (1.0f / (float)N_ROWS);
}

extern "C" void kernel_launch(void* const* d_in, const int* in_sizes, int n_in,
                              void* d_out, int out_size, void* d_ws, size_t ws_size,
                              hipStream_t stream) {
    const float* feature = (const float*)d_in[0];
    // ws layout: pos[8192] f32 | den[8192] f32 | Xb[8192*128] bf16
    float* pos = (float*)d_ws;
    float* den = pos + N_ROWS;
    __hip_bfloat16* Xb = (__hip_bfloat16*)(den + N_ROWS);

    norm_kernel<<<N_ROWS / 4, 256, 0, stream>>>(feature, Xb, pos, den);
    gram_kernel<<<dim3(128, 65), 256, 0, stream>>>(Xb, pos, den);
    loss_kernel<<<1, 256, 0, stream>>>(pos, den, (float*)d_out);
}